// Round 4
// baseline (1609.454 us; speedup 1.0000x reference)
//
#include <hip/hip_runtime.h>

#define NB 256
#define NT 1000
#define ND 64
#define NH 128
#define NTHR 1024

typedef _Float16 h2 __attribute__((ext_vector_type(2)));

__device__ __forceinline__ uint pk(float a, float b) {
    return __builtin_bit_cast(uint, __builtin_amdgcn_cvt_pkrtz(a, b));
}
__device__ __forceinline__ float fdot2u(uint a, uint b, float c) {
#if __has_builtin(__builtin_amdgcn_fdot2)
    return __builtin_amdgcn_fdot2(__builtin_bit_cast(h2, a),
                                  __builtin_bit_cast(h2, b), c, false);
#else
    h2 ha = __builtin_bit_cast(h2, a), hb = __builtin_bit_cast(h2, b);
    return c + (float)ha.x * (float)hb.x + (float)ha.y * (float)hb.y;
#endif
}
__device__ __forceinline__ float sigmoid_f(float x) {
    float e = __builtin_amdgcn_exp2f(-1.4426950408889634f * x);
    return __builtin_amdgcn_rcpf(1.0f + e);
}
__device__ __forceinline__ float tanh_f(float x) {
    float e = __builtin_amdgcn_exp2f(-2.8853900817779268f * x);
    return 2.0f * __builtin_amdgcn_rcpf(1.0f + e) - 1.0f;
}
// load 8 consecutive f32, pack to 4 f16x2 regs
__device__ __forceinline__ void ld8(const float* p, uint* d) {
    const float4 A = *(const float4*)p;
    const float4 B = *(const float4*)(p + 4);
    d[0] = pk(A.x, A.y); d[1] = pk(A.z, A.w);
    d[2] = pk(B.x, B.y); d[3] = pk(B.z, B.w);
}
#define PIN(v) asm volatile("" : "+v"(v))

__global__ __launch_bounds__(NTHR, 4) void gruode_fused(
    const float* __restrict__ x,      // (B,T,D)
    const float* __restrict__ tps,    // (T)
    const int*   __restrict__ mask,   // (B,T)
    const float* __restrict__ W_ih,   // (384,64)
    const float* __restrict__ W_hh,   // (384,128)
    const float* __restrict__ b_ih,   // (384)
    const float* __restrict__ b_hh,   // (384)
    const float* __restrict__ nW1,    // (128,128)
    const float* __restrict__ nb1,    // (128)
    const float* __restrict__ nW2,    // (128,128)
    const float* __restrict__ nb2,    // (128)
    const float* __restrict__ W_out,  // (128,128)
    const float* __restrict__ b_out,  // (128)
    float* __restrict__ out)          // (B,128)
{
    __shared__ __align__(16) _Float16 sh_h[2][NH];
    __shared__ __align__(16) _Float16 sh_tmp[NH];
    __shared__ __align__(16) _Float16 sh_ode[NH];
    __shared__ float sh_eo[NH];
    __shared__ float sh_dt[NT];
    __shared__ int   sh_m[NT];

    const int tid = threadIdx.x;
    const int j   = tid >> 3;       // output row 0..127
    const int q   = tid & 7;        // K-eighth
    const int b   = blockIdx.x;
    const int kb  = q * 16;         // f16/f32 col base for H-dots
    const int qb  = q * 32;         // byte base within a 128-f16 row
    const int kbi = q * 8;          // f32 col base for D-dots
    // bank swizzle: chunk i reads 16B at byte qb + wsel(i)*16.
    // wsel: q0-3 use chunk i, q4-7 use chunk i^1 -> per-instr the 8 q-groups
    // cover all 32 banks exactly (verified: bytes {0,32,64,96,144,176,208,240}).
    const int w0 = (q >> 2) & 1;
    const int w1_ = w0 ^ 1;

    // ---- stage all weights into f16x2 registers (one-time), pre-swizzled ----
    uint W1r[2][4], W2r[2][4], Whr[2][4], Whz[2][4], Whn[2][4];
    uint wir[4], wiz[4], win[4];
    ld8(nW1  + (j      )*NH + kb + w0 *8, W1r[0]);
    ld8(nW1  + (j      )*NH + kb + w1_*8, W1r[1]);
    ld8(nW2  + (j      )*NH + kb + w0 *8, W2r[0]);
    ld8(nW2  + (j      )*NH + kb + w1_*8, W2r[1]);
    ld8(W_hh + (j      )*NH + kb + w0 *8, Whr[0]);
    ld8(W_hh + (j      )*NH + kb + w1_*8, Whr[1]);
    ld8(W_hh + (j + 128)*NH + kb + w0 *8, Whz[0]);
    ld8(W_hh + (j + 128)*NH + kb + w1_*8, Whz[1]);
    ld8(W_hh + (j + 256)*NH + kb + w0 *8, Whn[0]);
    ld8(W_hh + (j + 256)*NH + kb + w1_*8, Whn[1]);
    ld8(W_ih + (j      )*ND + kbi, wir);
    ld8(W_ih + (j + 128)*ND + kbi, wiz);
    ld8(W_ih + (j + 256)*ND + kbi, win);
    float bb1   = nb1[j];
    float bb2   = nb2[j];
    float brz_r = b_ih[j]       + b_hh[j];
    float brz_z = b_ih[j + 128] + b_hh[j + 128];
    float bin_n = b_ih[j + 256];
    float bhn_n = b_hh[j + 256];

#pragma unroll
    for (int i = 0; i < 2; ++i)
#pragma unroll
        for (int k = 0; k < 4; ++k) {
            PIN(W1r[i][k]); PIN(W2r[i][k]);
            PIN(Whr[i][k]); PIN(Whz[i][k]); PIN(Whn[i][k]);
        }
#pragma unroll
    for (int k = 0; k < 4; ++k) { PIN(wir[k]); PIN(wiz[k]); PIN(win[k]); }
    PIN(bb1); PIN(bb2); PIN(brz_r); PIN(brz_z); PIN(bin_n); PIN(bhn_n);

    // ---- stage dt / mask into LDS; init h ----
    for (int s = tid; s < NT; s += NTHR) {
        sh_dt[s] = (s == 0) ? 0.0f : (tps[s] - tps[s - 1]);
        sh_m[s]  = mask[b * NT + s];
    }
    if (tid < NH) sh_h[0][tid] = (_Float16)0.0f;
    __syncthreads();

    float hlast = 0.0f;
    int   seen  = 0;

    // software prefetch of x / dt / mask (one step ahead)
    const float* xbase = x + (size_t)b * NT * ND + kbi;
    float4 xa = *(const float4*)(xbase);
    float4 xb = *(const float4*)(xbase + 4);
    float dtc = sh_dt[0];
    int   mc  = sh_m[0];

    for (int s = 0; s < NT; ++s) {
        const int   cur = s & 1, nxt = cur ^ 1;
        const int   m   = mc;                    // uniform per block
        const float dte = seen ? dtc : 0.0f;     // r_fill freeze (uniform)

        // issue next-step prefetch (fully off critical path)
        const int sn = (s + 1 < NT) ? (s + 1) : s;
        const float* xr = xbase + (size_t)sn * ND;
        const float4 xa_n = *(const float4*)(xr);
        const float4 xb_n = *(const float4*)(xr + 4);
        const float dt_n = sh_dt[sn];
        const int   m_n  = sh_m[sn];

        // pack x and compute input-gate partial dots (independent of h chain)
        uint xh[4];
        xh[0] = pk(xa.x, xa.y); xh[1] = pk(xa.z, xa.w);
        xh[2] = pk(xb.x, xb.y); xh[3] = pk(xb.z, xb.w);
        float gr = 0.0f, gz = 0.0f, gn = 0.0f;
#pragma unroll
        for (int k = 0; k < 4; ++k) {
            gr = fdot2u(wir[k], xh[k], gr);
            gz = fdot2u(wiz[k], xh[k], gz);
            gn = fdot2u(win[k], xh[k], gn);
        }

        const float hj = (float)sh_h[cur][j];
        float hode_j;
        const _Float16* hsrc;

        if (dte != 0.0f) {
            // stage 1: tmp = tanh(W1 h + b1)
            float a1 = 0.0f;
            {
                const uint4 hv = *(const uint4*)((const char*)&sh_h[cur][0] + qb + w0*16);
                a1 = fdot2u(W1r[0][0], hv.x, a1); a1 = fdot2u(W1r[0][1], hv.y, a1);
                a1 = fdot2u(W1r[0][2], hv.z, a1); a1 = fdot2u(W1r[0][3], hv.w, a1);
            }
            {
                const uint4 hv = *(const uint4*)((const char*)&sh_h[cur][0] + qb + w1_*16);
                a1 = fdot2u(W1r[1][0], hv.x, a1); a1 = fdot2u(W1r[1][1], hv.y, a1);
                a1 = fdot2u(W1r[1][2], hv.z, a1); a1 = fdot2u(W1r[1][3], hv.w, a1);
            }
            a1 += __shfl_xor(a1, 1); a1 += __shfl_xor(a1, 2); a1 += __shfl_xor(a1, 4);
            if (q == 0) sh_tmp[j] = (_Float16)tanh_f(a1 + bb1);
            __syncthreads();

            // stage 2: h_ode = h + dt * (W2 tmp + b2)
            float a2 = 0.0f;
            {
                const uint4 hv = *(const uint4*)((const char*)sh_tmp + qb + w0*16);
                a2 = fdot2u(W2r[0][0], hv.x, a2); a2 = fdot2u(W2r[0][1], hv.y, a2);
                a2 = fdot2u(W2r[0][2], hv.z, a2); a2 = fdot2u(W2r[0][3], hv.w, a2);
            }
            {
                const uint4 hv = *(const uint4*)((const char*)sh_tmp + qb + w1_*16);
                a2 = fdot2u(W2r[1][0], hv.x, a2); a2 = fdot2u(W2r[1][1], hv.y, a2);
                a2 = fdot2u(W2r[1][2], hv.z, a2); a2 = fdot2u(W2r[1][3], hv.w, a2);
            }
            a2 += __shfl_xor(a2, 1); a2 += __shfl_xor(a2, 2); a2 += __shfl_xor(a2, 4);
            hode_j = hj + dte * (a2 + bb2);
            if (q == 0) sh_ode[j] = (_Float16)hode_j;
            __syncthreads();
            hsrc = sh_ode;
        } else {
            hode_j = hj;
            hsrc = &sh_h[cur][0];
        }

        // stage 3: GRU cell recurrent dots
        float ar = 0.0f, az = 0.0f, an = 0.0f;
        {
            const uint4 hv = *(const uint4*)((const char*)hsrc + qb + w0*16);
            ar = fdot2u(Whr[0][0], hv.x, ar); ar = fdot2u(Whr[0][1], hv.y, ar);
            ar = fdot2u(Whr[0][2], hv.z, ar); ar = fdot2u(Whr[0][3], hv.w, ar);
            az = fdot2u(Whz[0][0], hv.x, az); az = fdot2u(Whz[0][1], hv.y, az);
            az = fdot2u(Whz[0][2], hv.z, az); az = fdot2u(Whz[0][3], hv.w, az);
            an = fdot2u(Whn[0][0], hv.x, an); an = fdot2u(Whn[0][1], hv.y, an);
            an = fdot2u(Whn[0][2], hv.z, an); an = fdot2u(Whn[0][3], hv.w, an);
        }
        {
            const uint4 hv = *(const uint4*)((const char*)hsrc + qb + w1_*16);
            ar = fdot2u(Whr[1][0], hv.x, ar); ar = fdot2u(Whr[1][1], hv.y, ar);
            ar = fdot2u(Whr[1][2], hv.z, ar); ar = fdot2u(Whr[1][3], hv.w, ar);
            az = fdot2u(Whz[1][0], hv.x, az); az = fdot2u(Whz[1][1], hv.y, az);
            az = fdot2u(Whz[1][2], hv.z, az); az = fdot2u(Whz[1][3], hv.w, az);
            an = fdot2u(Whn[1][0], hv.x, an); an = fdot2u(Whn[1][1], hv.y, an);
            an = fdot2u(Whn[1][2], hv.z, an); an = fdot2u(Whn[1][3], hv.w, an);
        }
        float sr = ar + gr, sz = az + gz;
        sr += __shfl_xor(sr, 1); sr += __shfl_xor(sr, 2); sr += __shfl_xor(sr, 4);
        sz += __shfl_xor(sz, 1); sz += __shfl_xor(sz, 2); sz += __shfl_xor(sz, 4);
        an += __shfl_xor(an, 1); an += __shfl_xor(an, 2); an += __shfl_xor(an, 4);
        gn += __shfl_xor(gn, 1); gn += __shfl_xor(gn, 2); gn += __shfl_xor(gn, 4);

        const float r = sigmoid_f(sr + brz_r);
        const float z = sigmoid_f(sz + brz_z);
        const float n = tanh_f(gn + bin_n + r * (an + bhn_n));
        const float hnew = m ? ((1.0f - z) * n + z * hode_j) : hode_j;

        if (q == 0) sh_h[nxt][j] = (_Float16)hnew;  // ping-pong write
        if (m) hlast = hnew;
        seen |= m;
        xa = xa_n; xb = xb_n; dtc = dt_n; mc = m_n;
        __syncthreads();
    }

    // epilogue (f32): out = W_out @ h_last + b_out
    if (q == 0) sh_eo[j] = hlast;
    __syncthreads();
    float ao = 0.0f;
#pragma unroll
    for (int i = 0; i < 4; ++i) {
        const float4 wv = *(const float4*)(W_out + j*NH + kb + i*4);
        const float4 hv = *(const float4*)(sh_eo + kb + i*4);
        ao += wv.x*hv.x + wv.y*hv.y + wv.z*hv.z + wv.w*hv.w;
    }
    ao += __shfl_xor(ao, 1); ao += __shfl_xor(ao, 2); ao += __shfl_xor(ao, 4);
    if (q == 0) out[b*NH + j] = ao + b_out[j];
}

extern "C" void kernel_launch(void* const* d_in, const int* in_sizes, int n_in,
                              void* d_out, int out_size, void* d_ws, size_t ws_size,
                              hipStream_t stream) {
    const float* x     = (const float*)d_in[0];
    const float* tps   = (const float*)d_in[1];
    const int*   mask  = (const int*)  d_in[2];
    const float* W_ih  = (const float*)d_in[3];
    const float* W_hh  = (const float*)d_in[4];
    const float* b_ih  = (const float*)d_in[5];
    const float* b_hh  = (const float*)d_in[6];
    const float* nW1   = (const float*)d_in[7];
    const float* nb1   = (const float*)d_in[8];
    const float* nW2   = (const float*)d_in[9];
    const float* nb2   = (const float*)d_in[10];
    const float* W_out = (const float*)d_in[11];
    const float* b_out = (const float*)d_in[12];
    float* out = (float*)d_out;

    gruode_fused<<<dim3(NB), dim3(NTHR), 0, stream>>>(
        x, tps, mask, W_ih, W_hh, b_ih, b_hh,
        nW1, nb1, nW2, nb2, W_out, b_out, out);
}

// Round 5
// 1413.231 us; speedup vs baseline: 1.1388x; 1.1388x over previous
//
#include <hip/hip_runtime.h>

#define NB 256
#define NT 1000
#define ND 64
#define NH 128

typedef _Float16 h2 __attribute__((ext_vector_type(2)));

__device__ __forceinline__ uint pk(float a, float b) {
    return __builtin_bit_cast(uint, __builtin_amdgcn_cvt_pkrtz(a, b));
}
__device__ __forceinline__ float fdot2u(uint a, uint b, float c) {
#if __has_builtin(__builtin_amdgcn_fdot2)
    return __builtin_amdgcn_fdot2(__builtin_bit_cast(h2, a),
                                  __builtin_bit_cast(h2, b), c, false);
#else
    h2 ha = __builtin_bit_cast(h2, a), hb = __builtin_bit_cast(h2, b);
    return c + (float)ha.x * (float)hb.x + (float)ha.y * (float)hb.y;
#endif
}
__device__ __forceinline__ float sigmoid_f(float x) {
    float e = __builtin_amdgcn_exp2f(-1.4426950408889634f * x);
    return __builtin_amdgcn_rcpf(1.0f + e);
}
__device__ __forceinline__ float tanh_f(float x) {
    float e = __builtin_amdgcn_exp2f(-2.8853900817779268f * x);
    return 2.0f * __builtin_amdgcn_rcpf(1.0f + e) - 1.0f;
}
// load 8 consecutive f32, pack to 4 f16x2 regs
__device__ __forceinline__ void ld8(const float* p, uint* d) {
    const float4 A = *(const float4*)p;
    const float4 B = *(const float4*)(p + 4);
    d[0] = pk(A.x, A.y); d[1] = pk(A.z, A.w);
    d[2] = pk(B.x, B.y); d[3] = pk(B.z, B.w);
}
#define PIN(v) asm volatile("" : "+v"(v))

__global__
__attribute__((amdgpu_flat_work_group_size(512, 512)))
__attribute__((amdgpu_waves_per_eu(2, 2)))   // pin occupancy target -> 256-VGPR budget
void gruode_fused(
    const float* __restrict__ x,      // (B,T,D)
    const float* __restrict__ tps,    // (T)
    const int*   __restrict__ mask,   // (B,T)
    const float* __restrict__ W_ih,   // (384,64)
    const float* __restrict__ W_hh,   // (384,128)
    const float* __restrict__ b_ih,   // (384)
    const float* __restrict__ b_hh,   // (384)
    const float* __restrict__ nW1,    // (128,128)
    const float* __restrict__ nb1,    // (128)
    const float* __restrict__ nW2,    // (128,128)
    const float* __restrict__ nb2,    // (128)
    const float* __restrict__ W_out,  // (128,128)
    const float* __restrict__ b_out,  // (128)
    float* __restrict__ out)          // (B,128)
{
    __shared__ __align__(16) _Float16 sh_h[2][NH];
    __shared__ __align__(16) _Float16 sh_tmp[NH];
    __shared__ __align__(16) _Float16 sh_ode[NH];
    __shared__ float sh_eo[NH];
    __shared__ float sh_dt[NT];
    __shared__ int   sh_m[NT];

    const int tid = threadIdx.x;
    const int j   = tid >> 2;   // output row 0..127
    const int q   = tid & 3;    // K-quarter
    const int b   = blockIdx.x;
    const int kb  = q * 32;     // f16/f32 col base for H-dots
    const int qb  = q * 64;     // byte base within a 128-f16 row
    const int kbi = q * 16;     // f32 col base for D-dots

    // bank swizzle (verified 0 conflicts in r3): chunk i reads 16B at byte
    // qb + w_*16 with w_ = (i + (q>>1)) & 3 -> per-instr the 4 q-groups land
    // on disjoint bank quads.
#define WSEL(i) (((i) + (q >> 1)) & 3)

    // ---- stage all weights into f16x2 registers (one-time), pre-swizzled ----
    uint w1[4][4], w2[4][4], whr[4][4], whz[4][4], whn[4][4];
    uint wir[8], wiz[8], win[8];
#pragma unroll
    for (int i = 0; i < 4; ++i) {
        const int c = kb + (WSEL(i) << 3);
        ld8(nW1  + (j      )*NH + c, w1[i]);
        ld8(nW2  + (j      )*NH + c, w2[i]);
        ld8(W_hh + (j      )*NH + c, whr[i]);
        ld8(W_hh + (j + 128)*NH + c, whz[i]);
        ld8(W_hh + (j + 256)*NH + c, whn[i]);
    }
    ld8(W_ih + (j      )*ND + kbi,     wir);
    ld8(W_ih + (j      )*ND + kbi + 8, wir + 4);
    ld8(W_ih + (j + 128)*ND + kbi,     wiz);
    ld8(W_ih + (j + 128)*ND + kbi + 8, wiz + 4);
    ld8(W_ih + (j + 256)*ND + kbi,     win);
    ld8(W_ih + (j + 256)*ND + kbi + 8, win + 4);
    float bb1   = nb1[j];
    float bb2   = nb2[j];
    float brz_r = b_ih[j]       + b_hh[j];
    float brz_z = b_ih[j + 128] + b_hh[j + 128];
    float bin_n = b_ih[j + 256];
    float bhn_n = b_hh[j + 256];

#pragma unroll
    for (int i = 0; i < 4; ++i)
#pragma unroll
        for (int k = 0; k < 4; ++k) {
            PIN(w1[i][k]); PIN(w2[i][k]);
            PIN(whr[i][k]); PIN(whz[i][k]); PIN(whn[i][k]);
        }
#pragma unroll
    for (int k = 0; k < 8; ++k) { PIN(wir[k]); PIN(wiz[k]); PIN(win[k]); }
    PIN(bb1); PIN(bb2); PIN(brz_r); PIN(brz_z); PIN(bin_n); PIN(bhn_n);

    // ---- stage dt / mask into LDS; init h ----
    for (int s = tid; s < NT; s += 512) {
        sh_dt[s] = (s == 0) ? 0.0f : (tps[s] - tps[s - 1]);
        sh_m[s]  = mask[b * NT + s];
    }
    if (tid < NH) sh_h[0][tid] = (_Float16)0.0f;
    __syncthreads();

    float hlast = 0.0f;
    int   seen  = 0;

    // software prefetch (one step ahead): x slice + dt + mask
    const float* xbase = x + (size_t)b * NT * ND + kbi;
    float4 xc0 = *(const float4*)(xbase);
    float4 xc1 = *(const float4*)(xbase + 4);
    float4 xc2 = *(const float4*)(xbase + 8);
    float4 xc3 = *(const float4*)(xbase + 12);
    float dtc = sh_dt[0];
    int   mc  = sh_m[0];

    for (int s = 0; s < NT; ++s) {
        const int   cur = s & 1, nxt = cur ^ 1;
        const int   m   = mc;                    // uniform per block
        const float dte = seen ? dtc : 0.0f;     // r_fill freeze (uniform)

        // issue next-step prefetch (off critical path; waits land at rotate)
        const int sn = (s + 1 < NT) ? (s + 1) : s;
        const float* xr = xbase + (size_t)sn * ND;
        const float4 xn0 = *(const float4*)(xr);
        const float4 xn1 = *(const float4*)(xr + 4);
        const float4 xn2 = *(const float4*)(xr + 8);
        const float4 xn3 = *(const float4*)(xr + 12);
        const float dt_n = sh_dt[sn];
        const int   m_n  = sh_m[sn];

        // pack x, input-gate dots (independent of h chain)
        uint xh[8];
        xh[0] = pk(xc0.x, xc0.y); xh[1] = pk(xc0.z, xc0.w);
        xh[2] = pk(xc1.x, xc1.y); xh[3] = pk(xc1.z, xc1.w);
        xh[4] = pk(xc2.x, xc2.y); xh[5] = pk(xc2.z, xc2.w);
        xh[6] = pk(xc3.x, xc3.y); xh[7] = pk(xc3.z, xc3.w);
        float gr = 0.0f, gz = 0.0f, gn = 0.0f;
#pragma unroll
        for (int k = 0; k < 8; ++k) {
            gr = fdot2u(wir[k], xh[k], gr);
            gz = fdot2u(wiz[k], xh[k], gz);
            gn = fdot2u(win[k], xh[k], gn);
        }

        const float hj = (float)sh_h[cur][j];
        float hode_j;
        const _Float16* hsrc;

        if (dte != 0.0f) {
            // stage 1: tmp = tanh(W1 h + b1)   (2 partial chains for ILP)
            float a1a = 0.0f, a1b = 0.0f;
#pragma unroll
            for (int i = 0; i < 4; ++i) {
                const uint4 hv = *(const uint4*)((const char*)&sh_h[cur][0] + qb + WSEL(i)*16);
                float& acc = (i & 1) ? a1b : a1a;
                acc = fdot2u(w1[i][0], hv.x, acc); acc = fdot2u(w1[i][1], hv.y, acc);
                acc = fdot2u(w1[i][2], hv.z, acc); acc = fdot2u(w1[i][3], hv.w, acc);
            }
            float a1 = a1a + a1b;
            a1 += __shfl_xor(a1, 1); a1 += __shfl_xor(a1, 2);
            if (q == 0) sh_tmp[j] = (_Float16)tanh_f(a1 + bb1);
            __syncthreads();

            // stage 2: h_ode = h + dt * (W2 tmp + b2)
            float a2a = 0.0f, a2b = 0.0f;
#pragma unroll
            for (int i = 0; i < 4; ++i) {
                const uint4 hv = *(const uint4*)((const char*)sh_tmp + qb + WSEL(i)*16);
                float& acc = (i & 1) ? a2b : a2a;
                acc = fdot2u(w2[i][0], hv.x, acc); acc = fdot2u(w2[i][1], hv.y, acc);
                acc = fdot2u(w2[i][2], hv.z, acc); acc = fdot2u(w2[i][3], hv.w, acc);
            }
            float a2 = a2a + a2b;
            a2 += __shfl_xor(a2, 1); a2 += __shfl_xor(a2, 2);
            hode_j = hj + dte * (a2 + bb2);
            if (q == 0) sh_ode[j] = (_Float16)hode_j;
            __syncthreads();
            hsrc = sh_ode;
        } else {
            hode_j = hj;
            hsrc = &sh_h[cur][0];
        }

        // stage 3: GRU recurrent dots (3 chains)
        float ar = 0.0f, az = 0.0f, an = 0.0f;
#pragma unroll
        for (int i = 0; i < 4; ++i) {
            const uint4 hv = *(const uint4*)((const char*)hsrc + qb + WSEL(i)*16);
            ar = fdot2u(whr[i][0], hv.x, ar); ar = fdot2u(whr[i][1], hv.y, ar);
            ar = fdot2u(whr[i][2], hv.z, ar); ar = fdot2u(whr[i][3], hv.w, ar);
            az = fdot2u(whz[i][0], hv.x, az); az = fdot2u(whz[i][1], hv.y, az);
            az = fdot2u(whz[i][2], hv.z, az); az = fdot2u(whz[i][3], hv.w, az);
            an = fdot2u(whn[i][0], hv.x, an); an = fdot2u(whn[i][1], hv.y, an);
            an = fdot2u(whn[i][2], hv.z, an); an = fdot2u(whn[i][3], hv.w, an);
        }
        float sr = ar + gr, sz = az + gz;
        sr += __shfl_xor(sr, 1); sr += __shfl_xor(sr, 2);
        sz += __shfl_xor(sz, 1); sz += __shfl_xor(sz, 2);
        an += __shfl_xor(an, 1); an += __shfl_xor(an, 2);
        gn += __shfl_xor(gn, 1); gn += __shfl_xor(gn, 2);

        const float r = sigmoid_f(sr + brz_r);
        const float z = sigmoid_f(sz + brz_z);
        const float n = tanh_f(gn + bin_n + r * (an + bhn_n));
        const float hnew = m ? ((1.0f - z) * n + z * hode_j) : hode_j;

        if (q == 0) sh_h[nxt][j] = (_Float16)hnew;  // ping-pong write
        if (m) hlast = hnew;
        seen |= m;
        xc0 = xn0; xc1 = xn1; xc2 = xn2; xc3 = xn3; dtc = dt_n; mc = m_n;
        __syncthreads();
    }

    // epilogue (f32): out = W_out @ h_last + b_out
    if (q == 0) sh_eo[j] = hlast;
    __syncthreads();
    float ao = 0.0f;
#pragma unroll
    for (int i = 0; i < 8; ++i) {
        const int c = kb + ((((i) + 2 * q) & 7) << 2);
        const float4 wv = *(const float4*)(W_out + j*NH + c);
        const float4 hv = *(const float4*)(sh_eo + c);
        ao += wv.x*hv.x + wv.y*hv.y + wv.z*hv.z + wv.w*hv.w;
    }
    ao += __shfl_xor(ao, 1); ao += __shfl_xor(ao, 2);
    if (q == 0) out[b*NH + j] = ao + b_out[j];
}

extern "C" void kernel_launch(void* const* d_in, const int* in_sizes, int n_in,
                              void* d_out, int out_size, void* d_ws, size_t ws_size,
                              hipStream_t stream) {
    const float* x     = (const float*)d_in[0];
    const float* tps   = (const float*)d_in[1];
    const int*   mask  = (const int*)  d_in[2];
    const float* W_ih  = (const float*)d_in[3];
    const float* W_hh  = (const float*)d_in[4];
    const float* b_ih  = (const float*)d_in[5];
    const float* b_hh  = (const float*)d_in[6];
    const float* nW1   = (const float*)d_in[7];
    const float* nb1   = (const float*)d_in[8];
    const float* nW2   = (const float*)d_in[9];
    const float* nb2   = (const float*)d_in[10];
    const float* W_out = (const float*)d_in[11];
    const float* b_out = (const float*)d_in[12];
    float* out = (float*)d_out;

    gruode_fused<<<dim3(NB), dim3(512), 0, stream>>>(
        x, tps, mask, W_ih, W_hh, b_ih, b_hh,
        nW1, nb1, nW2, nb2, W_out, b_out, out);
}